// Round 10
// baseline (100.969 us; speedup 1.0000x reference)
//
#include <hip/hip_runtime.h>
#include <hip/hip_fp16.h>

// KPConv fused via MFMA for MI355X (gfx950) — round 10.
// B=2, N=32768, K=32 neighbors, S=15 kernel pts, C_in=C_out=128.
//
// = round 9 EXCEPT __launch_bounds__(512, 2).
// Post-mortem r8/r9: both spilled (~32 KB/block scratch -> +65 MB HBM write,
// +30 MB fetch) because __launch_bounds__(512,4) capped VGPRs at 64 (the
// 2nd arg behaves as min BLOCKS/CU: 4 blocks x 8 waves = 8 waves/SIMD ->
// 64 regs), while the kernel needs ~95 live. (512,2) -> 128-reg cap; LDS
// (74.75 KB) already limits residency to 2 blocks/CU, so no occupancy loss.
//
// 32x32x16 f16 fragment layouts (HW-verified by rounds 8/9 passing):
//   A: lane l holds A[row=l&31][k=(l>>5)*8+j]
//   B: lane l holds B[k=(l>>5)*8+j][col=l&31]
//   C/D: col=lane&31, row=(reg&3)+8*(reg>>2)+4*(lane>>5)

typedef __attribute__((ext_vector_type(8))) _Float16 f16x8;
typedef __attribute__((ext_vector_type(16))) float f32x16;

constexpr int KS  = 15;      // kernel points
constexpr int C   = 128;     // C_in = C_out
constexpr int P   = 32;      // points per block
constexpr int NPT = 32768;   // points per batch
constexpr int NKS = 120;     // total ksteps (1920/16)
constexpr int SLOTS = 16;    // max survivors per point   (P(>16) ~ 1e-14)
constexpr int PAIRS = 88;    // max survivors per block   (mean 46, +6.3 sd)

constexpr float R2CUT = 0.0513f;          // beyond: all 15 kw < ~3e-8
constexpr float NEGK  = -801.4972449f;    // -1/(2*0.03^2) * log2(e)

// Pack W[k=1920][o=128] f32 -> Wp[nt 4][ks 120][lane 64][j 8] f16.
// B-frag (32x32x16): lane l holds B[k = ks*16 + (l>>5)*8 + j][col = l&31].
__global__ void wpack_kernel(const float* __restrict__ W,
                             unsigned short* __restrict__ Wp) {
    const int t  = blockIdx.x * 256 + threadIdx.x;   // 30720 threads
    const int fl = t & 63;
    const int ks = (t >> 6) % NKS;
    const int nt = t / (NKS * 64);
    const int o     = nt * 32 + (fl & 31);
    const int kbase = ks * 16 + (fl >> 5) * 8;
    __half v[8] __attribute__((aligned(16)));
    #pragma unroll
    for (int j = 0; j < 8; ++j)
        v[j] = __float2half_rn(W[(size_t)(kbase + j) * C + o]);
    *(uint4*)(Wp + (size_t)t * 8) = *(const uint4*)v;
}

__launch_bounds__(512, 2)
__global__ void kpconv_main(const float* __restrict__ xyz,
                            const float* __restrict__ feat,
                            const int*   __restrict__ nidx,
                            const float* __restrict__ kpts,
                            const unsigned short* __restrict__ Wp,
                            const float* __restrict__ bias,
                            float* __restrict__ out)
{
    // A chunk buffer: up to 64 ksteps x 64 lanes x 16 B = 65536 B
    __shared__ __align__(16) unsigned short a_lds[32768];
    __shared__ __align__(16) __half2        s_kw2[PAIRS][16];        // 5632 B
    __shared__ int            s_gslot[P][SLOTS];                     // 2048 B
    __shared__ unsigned char  s_slotid[P][SLOTS];                    //  512 B
    __shared__ int            s_cnt[P];
    __shared__ int            s_pcnt;
    __shared__ float          s_ctr[P][3];
    __shared__ float          s_kp[KS][3];

    // survivor rel-positions alias a_lds (dead after phase 1b)
    float4* const s_rel = reinterpret_cast<float4*>(a_lds);          // 1408 B

    const int tid  = threadIdx.x;
    const int pt0  = blockIdx.x * P;
    const int boff = pt0 & NPT;              // batch row offset (0 or 32768)

    // ---- phase 0 ----
    if (tid < 128) ((unsigned*)s_slotid)[tid] = 0xFFFFFFFFu;  // sentinels
    else if (tid < 160) s_cnt[tid - 128] = 0;
    else if (tid == 160) s_pcnt = 0;
    if (tid >= 192 && tid < 192 + P * 3)
        ((float*)s_ctr)[tid - 192] = xyz[(size_t)pt0 * 3 + (tid - 192)];
    if (tid >= 320 && tid < 320 + KS * 3)
        ((float*)s_kp)[tid - 320] = kpts[tid - 320];
    __syncthreads();

    // ---- phase 1: gate 1024 pairs, compact survivors ----
    #pragma unroll
    for (int i = 0; i < 2; ++i) {
        const int q = tid + 512 * i;
        const int p = q >> 5, k = q & 31;
        const int idx = nidx[(pt0 + p) * 32 + k];
        const float rx = xyz[(boff + idx) * 3 + 0] - s_ctr[p][0];
        const float ry = xyz[(boff + idx) * 3 + 1] - s_ctr[p][1];
        const float rz = xyz[(boff + idx) * 3 + 2] - s_ctr[p][2];
        if (rx * rx + ry * ry + rz * rz <= R2CUT) {
            const int slot = atomicAdd(&s_cnt[p], 1);
            if (slot < SLOTS) {
                const int pid = atomicAdd(&s_pcnt, 1);
                if (pid < PAIRS) {
                    s_slotid[p][slot] = (unsigned char)pid;
                    s_gslot[p][slot] = (boff + idx) << 7;  // feat row offset
                    s_rel[pid] = make_float4(rx, ry, rz, 0.f);
                }
            }
        }
    }
    __syncthreads();

    const int wv   = tid >> 6;         // 0..7
    const int lane = tid & 63;
    const int pcnt = __builtin_amdgcn_readfirstlane(min(s_pcnt, PAIRS));

    // ---- phase 1b: fully parallel kw (one (pid,s) per lane), splat half2 ----
    for (int t = tid; t < pcnt * 16; t += 512) {
        const int pid = t >> 4, s = t & 15;
        if (s < KS) {
            const float4 rel = s_rel[pid];
            const float dx = rel.x - s_kp[s][0];
            const float dy = rel.y - s_kp[s][1];
            const float dz = rel.z - s_kp[s][2];
            const float d2 = dx * dx + dy * dy + dz * dz;
            s_kw2[pid][s] = __half2half2(__float2half_rn(exp2f(d2 * NEGK)));
        } else {
            s_kw2[pid][15] = __float2half2_rn(0.f);
        }
    }
    __syncthreads();   // also: last read of s_rel before a_lds reuse

    const int pb4 = wv * 4;            // phase-2 point set: 4 per wave
    const int c2  = 2 * lane;          // channel pair
    const int nt  = wv & 3;            // phase-3 n-tile (32 cols)
    const int kq  = wv >> 2;           // phase-3 K-half

    int cnt_r[4]; int cmax = 0;
    #pragma unroll
    for (int pp = 0; pp < 4; ++pp) {
        int cc = s_cnt[pb4 + pp];
        cc = cc > SLOTS ? SLOTS : cc;
        cnt_r[pp] = __builtin_amdgcn_readfirstlane(cc);
        cmax = max(cmax, cnt_r[pp]);
    }

    // ---- phase 2: single-pass aggregation, all 15 s in registers ----
    __half2 agg[4][15];
    #pragma unroll
    for (int pp = 0; pp < 4; ++pp)
        #pragma unroll
        for (int s = 0; s < KS; ++s)
            agg[pp][s] = __float2half2_rn(0.f);

    for (int a = 0; a < cmax; ++a) {
        #pragma unroll
        for (int pp = 0; pp < 4; ++pp) {
            if (a < cnt_r[pp]) {                     // wave-uniform branch
                const int pt  = pb4 + pp;
                const int pid = s_slotid[pt][a];     // broadcast
                if (pid != 0xFF) {
                    const float2 f =
                        *(const float2*)&feat[s_gslot[pt][a] + c2];
                    const __half2 h = __float22half2_rn(f);
                    union { uint4 v[4]; __half2 h2[16]; } kw;
                    kw.v[0] = *(const uint4*)&s_kw2[pid][0];
                    kw.v[1] = *(const uint4*)&s_kw2[pid][4];
                    kw.v[2] = *(const uint4*)&s_kw2[pid][8];
                    kw.v[3] = *(const uint4*)&s_kw2[pid][12];
                    #pragma unroll
                    for (int s = 0; s < KS; ++s)
                        agg[pp][s] = __hfma2(kw.h2[s], h, agg[pp][s]);
                }
            }
        }
    }

    // ---- A-tile addressing ----
    // element (row, k): local ks = s*8 + lane/8 (s local to chunk),
    // kk = (2*lane)&15.  Flat word = s*2048 + (lane>>3)*256
    //   + ((kk>=8)<<7) + row*4 + ((kk&7)>>1), XOR-swizzled by bits 2-4.
    const unsigned sw = ((unsigned)(lane >> 3) & 7u) << 2;
    unsigned base_pp[4];
    #pragma unroll
    for (int pp = 0; pp < 4; ++pp)
        base_pp[pp] = ((unsigned)(lane >> 3) << 8) |
                      (((unsigned)lane & 4u) << 5) |
                      ((unsigned)(pb4 + pp) << 2) |
                      ((unsigned)lane & 3u);

    f32x16 acc = {};
    const char* const a_bytes = (const char*)a_lds;

    // ---- chunk A: s 0..7 (local ks 0..63) ----
    #pragma unroll
    for (int pp = 0; pp < 4; ++pp)
        #pragma unroll
        for (int s = 0; s < 8; ++s) {
            union { __half2 h; unsigned u; } cv; cv.h = agg[pp][s];
            ((unsigned*)a_lds)[(s * 2048 + base_pp[pp]) ^ sw] = cv.u;
        }
    __syncthreads();

    #pragma unroll
    for (int i = 0; i < 32; ++i) {
        const int ks = kq * 32 + i;            // local == global kstep here
        const f16x8 af = *(const f16x8*)
            (a_bytes + (((unsigned)(ks * 256 + lane * 4)
                         ^ (((unsigned)ks & 7u) << 2)) << 2));
        const f16x8 bf = *(const f16x8*)
            (Wp + ((size_t)(nt * NKS + ks) * 64 + lane) * 8);
        acc = __builtin_amdgcn_mfma_f32_32x32x16_f16(af, bf, acc, 0, 0, 0);
    }
    __syncthreads();

    // ---- chunk B: s 8..14 (local ks 0..55, global ks 64..119) ----
    #pragma unroll
    for (int pp = 0; pp < 4; ++pp)
        #pragma unroll
        for (int s = 0; s < 7; ++s) {
            union { __half2 h; unsigned u; } cv; cv.h = agg[pp][8 + s];
            ((unsigned*)a_lds)[(s * 2048 + base_pp[pp]) ^ sw] = cv.u;
        }
    __syncthreads();

    #pragma unroll
    for (int i = 0; i < 28; ++i) {
        const int ksl = kq * 28 + i;
        const int gks = 64 + ksl;
        const f16x8 af = *(const f16x8*)
            (a_bytes + (((unsigned)(ksl * 256 + lane * 4)
                         ^ (((unsigned)ksl & 7u) << 2)) << 2));
        const f16x8 bf = *(const f16x8*)
            (Wp + ((size_t)(nt * NKS + gks) * 64 + lane) * 8);
        acc = __builtin_amdgcn_mfma_f32_32x32x16_f16(af, bf, acc, 0, 0, 0);
    }
    __syncthreads();   // all MFMA LDS reads done before aliasing red

    // ---- split-K2 reduction: [reg][nt][lane] floats (2-way max = free) ----
    float* red = reinterpret_cast<float*>(a_lds);
    if (kq == 1) {
        #pragma unroll
        for (int r = 0; r < 16; ++r)
            red[r * 256 + nt * 64 + lane] = acc[r];
    }
    __syncthreads();
    if (kq == 0) {
        // C/D layout: col=lane&31, row=(r&3)+8*(r>>2)+4*(lane>>5)
        const int o = nt * 32 + (lane & 31);
        const float b = bias[o];
        const int rbase = pt0 + 4 * (lane >> 5);
        #pragma unroll
        for (int r = 0; r < 16; ++r) {
            const float v = acc[r] + red[r * 256 + nt * 64 + lane] + b;
            const int row = rbase + (r & 3) + 8 * (r >> 2);
            out[(size_t)row * C + o] = v;
        }
    }
}

extern "C" void kernel_launch(void* const* d_in, const int* in_sizes, int n_in,
                              void* d_out, int out_size, void* d_ws, size_t ws_size,
                              hipStream_t stream)
{
    const float* xyz  = (const float*)d_in[0];
    const float* feat = (const float*)d_in[1];
    const int*   nidx = (const int*)  d_in[2];
    const float* kpts = (const float*)d_in[3];
    const float* W    = (const float*)d_in[4];
    const float* bias = (const float*)d_in[5];
    float* out = (float*)d_out;

    unsigned short* Wp = (unsigned short*)d_ws;   // 491,520 B

    wpack_kernel<<<120, 256, 0, stream>>>(W, Wp);

    const int total_pts = in_sizes[0] / 3;        // 65536
    kpconv_main<<<total_pts / P, 512, 0, stream>>>(xyz, feat, nidx, kpts,
                                                   Wp, bias, out);
}

// Round 11
// 71.525 us; speedup vs baseline: 1.4117x; 1.4117x over previous
//
#include <hip/hip_runtime.h>
#include <hip/hip_fp16.h>

// KPConv fused via MFMA for MI355X (gfx950) — round 11.
// B=2, N=32768, K=32 neighbors, S=15 kernel pts, C_in=C_out=128.
//
// = round 7 (74.7 us, best) + ILP fixes; 32x32 path abandoned (r8-r10 all
// slower even spill-free: serial acc chain + 1 MFMA/B-load starves the
// scheduler).
//  1. __launch_bounds__(512,2): 128-VGPR cap (r7's (512,4) capped at 64 ->
//     VGPR=52, zero prefetch registers).
//  2. depth-4 B-fragment prefetch ring (static indices), prologue issued
//     before the A-tile LDS writes; ring refill crosses the chunk boundary.
//  3. phase-2 unrolled x2, load-first batching (8 gathers in flight).
//
// 16x16x32 f16 fragment layouts (HW-verified r2-r7):
//   A/B: lane l holds X[row|col=l&15][k=(l>>4)*8+j]
//   C/D: col=lane&15, row=(lane>>4)*4+reg

typedef __attribute__((ext_vector_type(8))) _Float16 f16x8;
typedef __attribute__((ext_vector_type(4))) float f32x4;

constexpr int KS  = 15;      // kernel points
constexpr int C   = 128;     // C_in = C_out
constexpr int P   = 32;      // points per block
constexpr int NPT = 32768;   // points per batch
constexpr int NKS = 60;      // total ksteps (15*128/32)
constexpr int SLOTS = 16;    // max survivors per point   (P(>16) ~ 1e-14)
constexpr int PAIRS = 88;    // max survivors per block   (mean 46, +6.3 sd)

constexpr float R2CUT = 0.0513f;          // beyond: all 15 kw < ~3e-8
constexpr float NEGK  = -801.4972449f;    // -1/(2*0.03^2) * log2(e)

__device__ __forceinline__ unsigned swz(unsigned gi) {
    gi ^= ((gi >> 4) & 3u) << 1;
    gi ^= (gi >> 6) & 1u;
    return gi;
}

// Pack W[k=1920][o=128] f32 -> Wp[nt 8][gks 60][lane 64][j 8] f16.
// B-frag (16x16x32): lane l holds B[kk = (l>>4)*8 + j][col = l&15].
__global__ void wpack_kernel(const float* __restrict__ W,
                             unsigned short* __restrict__ Wp) {
    const int t   = blockIdx.x * 256 + threadIdx.x;   // 30720 threads
    const int fl  = t & 63;
    const int gks = (t >> 6) % NKS;
    const int nt  = t / (NKS * 64);
    const int o     = nt * 16 + (fl & 15);
    const int kbase = gks * 32 + (fl >> 4) * 8;
    __half v[8] __attribute__((aligned(16)));
    #pragma unroll
    for (int j = 0; j < 8; ++j)
        v[j] = __float2half_rn(W[(size_t)(kbase + j) * C + o]);
    *(uint4*)(Wp + (size_t)t * 8) = *(const uint4*)v;
}

__launch_bounds__(512, 2)
__global__ void kpconv_main(const float* __restrict__ xyz,
                            const float* __restrict__ feat,
                            const int*   __restrict__ nidx,
                            const float* __restrict__ kpts,
                            const unsigned short* __restrict__ Wp,
                            const float* __restrict__ bias,
                            float* __restrict__ out)
{
    // A half-tile: 2 mt x 32 ks x 64 lanes x 16 B = 65536 B
    __shared__ __align__(16) unsigned short a_lds[2 * 32 * 64 * 8];
    __shared__ __align__(16) __half2        s_kw2[PAIRS][16];        // 5632 B
    __shared__ int            s_gidx[PAIRS];                         //  352 B
    __shared__ unsigned char  s_slotid[P][SLOTS];                    //  512 B
    __shared__ int            s_cnt[P];
    __shared__ int            s_pcnt;
    __shared__ float          s_ctr[P][3];
    __shared__ float          s_kp[KS][3];

    // survivor rel-positions alias a_lds (dead after phase 1b)
    float4* const s_rel = reinterpret_cast<float4*>(a_lds);          // 1408 B

    const int tid  = threadIdx.x;
    const int pt0  = blockIdx.x * P;
    const int boff = pt0 & NPT;              // batch row offset (0 or 32768)

    // ---- phase 0 ----
    if (tid < 128) ((unsigned*)s_slotid)[tid] = 0xFFFFFFFFu;  // sentinels
    if (tid < P) s_cnt[tid] = 0;
    if (tid == 480) s_pcnt = 0;
    if (tid < P * 3) ((float*)s_ctr)[tid] = xyz[(size_t)pt0 * 3 + tid];
    if (tid >= 128 && tid < 128 + KS * 3)
        ((float*)s_kp)[tid - 128] = kpts[tid - 128];
    __syncthreads();

    // ---- phase 1: gate 1024 pairs, compact survivors ----
    #pragma unroll
    for (int i = 0; i < 2; ++i) {
        const int q = tid + 512 * i;
        const int p = q >> 5, k = q & 31;
        const int idx = nidx[(pt0 + p) * 32 + k];
        const float rx = xyz[(boff + idx) * 3 + 0] - s_ctr[p][0];
        const float ry = xyz[(boff + idx) * 3 + 1] - s_ctr[p][1];
        const float rz = xyz[(boff + idx) * 3 + 2] - s_ctr[p][2];
        if (rx * rx + ry * ry + rz * rz <= R2CUT) {
            const int slot = atomicAdd(&s_cnt[p], 1);
            if (slot < SLOTS) {
                const int pid = atomicAdd(&s_pcnt, 1);
                if (pid < PAIRS) {
                    s_slotid[p][slot] = (unsigned char)pid;
                    s_gidx[pid] = (boff + idx) << 7;   // feature row offset
                    s_rel[pid] = make_float4(rx, ry, rz, 0.f);
                }
            }
        }
    }
    __syncthreads();

    const int wv   = tid >> 6;         // 0..7
    const int lane = tid & 63;
    const int pcnt = __builtin_amdgcn_readfirstlane(min(s_pcnt, PAIRS));

    // ---- phase 1b: fully parallel kw (one (pid,s) per lane), splat half2 ----
    for (int t = tid; t < pcnt * 16; t += 512) {
        const int pid = t >> 4, s = t & 15;
        if (s < KS) {
            const float4 rel = s_rel[pid];
            const float dx = rel.x - s_kp[s][0];
            const float dy = rel.y - s_kp[s][1];
            const float dz = rel.z - s_kp[s][2];
            const float d2 = dx * dx + dy * dy + dz * dz;
            s_kw2[pid][s] = __half2half2(__float2half_rn(exp2f(d2 * NEGK)));
        } else {
            s_kw2[pid][15] = __float2half2_rn(0.f);
        }
    }
    __syncthreads();   // also: last read of s_rel before a_lds reuse

    const int pb4 = wv * 4;            // phase-2 point set: 4 per wave
    const int c2  = 2 * lane;          // channel pair

    int cnt_r[4]; int cmax = 0;
    #pragma unroll
    for (int pp = 0; pp < 4; ++pp) {
        int cc = s_cnt[pb4 + pp];
        cc = cc > SLOTS ? SLOTS : cc;
        cnt_r[pp] = __builtin_amdgcn_readfirstlane(cc);
        cmax = max(cmax, cnt_r[pp]);
    }

    // ---- phase 2: single-pass aggregation, unrolled x2, load-first ----
    __half2 agg[4][15];
    #pragma unroll
    for (int pp = 0; pp < 4; ++pp)
        #pragma unroll
        for (int s = 0; s < KS; ++s)
            agg[pp][s] = __float2half2_rn(0.f);

    for (int a = 0; a < cmax; a += 2) {
        float2 fv[4][2]; int pidv[4][2]; bool av[4][2];
        #pragma unroll
        for (int pp = 0; pp < 4; ++pp) {
            #pragma unroll
            for (int u = 0; u < 2; ++u) {
                const int aa = a + u;
                av[pp][u] = false;
                if (aa < cnt_r[pp]) {                // wave-uniform
                    const int pid = s_slotid[pb4 + pp][aa];
                    if (pid != 0xFF) {
                        pidv[pp][u] = pid;
                        fv[pp][u] = *(const float2*)&feat[s_gidx[pid] + c2];
                        av[pp][u] = true;
                    }
                }
            }
        }
        #pragma unroll
        for (int pp = 0; pp < 4; ++pp) {
            #pragma unroll
            for (int u = 0; u < 2; ++u) {
                if (av[pp][u]) {
                    const int pid = pidv[pp][u];
                    const __half2 h = __float22half2_rn(fv[pp][u]);
                    union { uint4 v[4]; __half2 h2[16]; } kw;
                    kw.v[0] = *(const uint4*)&s_kw2[pid][0];
                    kw.v[1] = *(const uint4*)&s_kw2[pid][4];
                    kw.v[2] = *(const uint4*)&s_kw2[pid][8];
                    kw.v[3] = *(const uint4*)&s_kw2[pid][12];
                    #pragma unroll
                    for (int s = 0; s < KS; ++s)
                        agg[pp][s] = __hfma2(kw.h2[s], h, agg[pp][s]);
                }
            }
        }
    }

    // ---- swizzled LDS bases (write: word idx; read: byte offset) ----
    const int q2    = (lane >> 2) & 3;
    const int ksoff = lane >> 4;
    const int dsub  = lane & 3;

    int wbaseA[4], wbaseB[4];
    #pragma unroll
    for (int pp = 0; pp < 4; ++pp) {
        const int r   = pb4 + pp;
        const int wmt = r >> 4;
        const int fl  = (r & 15) + 16 * q2;
        wbaseA[pp] = (int)(swz((unsigned)((wmt * 32 + ksoff) * 64 + fl)) * 4
                           + dsub);
        wbaseB[pp] = (int)(swz((unsigned)((wmt * 28 + ksoff) * 64 + fl)) * 4
                           + dsub);
    }
    int rbA[2][2], rbB[2][2];          // [mt][ks parity] byte offsets
    #pragma unroll
    for (int mt = 0; mt < 2; ++mt)
        #pragma unroll
        for (int par = 0; par < 2; ++par) {
            rbA[mt][par] = (int)(swz((unsigned)((mt * 32 + par) * 64 + lane)) * 16);
            rbB[mt][par] = (int)(swz((unsigned)((mt * 28 + par) * 64 + lane)) * 16);
        }

    // per-wave B-fragment base (ntile = wv; each B-frag read once per block)
    const unsigned short* wp = Wp + ((size_t)(wv * NKS) * 64 + lane) * 8;

    f32x4 acc[2] = {};                 // C/D frags: [mt]
    const char* const a_bytes = (const char*)a_lds;

    // B prologue: first 4 fragments in flight before/under the A-writes
    f16x8 bq[4];
    #pragma unroll
    for (int i = 0; i < 4; ++i)
        bq[i] = *(const f16x8*)(wp + i * 512);

    // ---- phase 2.5a: write s0..7 (ks 0..31) ----
    #pragma unroll
    for (int pp = 0; pp < 4; ++pp)
        #pragma unroll
        for (int s = 0; s < 8; ++s) {
            union { __half2 h; unsigned u; } cv; cv.h = agg[pp][s];
            ((unsigned*)a_lds)[wbaseA[pp] + s * 1024] = cv.u;
        }
    __syncthreads();

    // ---- phase 3a: MFMA ks 0..31, depth-4 B ring ----
    #pragma unroll
    for (int ks = 0; ks < 32; ++ks) {
        const f16x8 bf = bq[ks & 3];
        bq[ks & 3] = *(const f16x8*)(wp + (ks + 4) * 512);   // 35 max < 60
        const f16x8 af0 = *(const f16x8*)(a_bytes + rbA[0][ks & 1]
                                          + (ks >> 1) * 2048);
        const f16x8 af1 = *(const f16x8*)(a_bytes + rbA[1][ks & 1]
                                          + (ks >> 1) * 2048);
        acc[0] = __builtin_amdgcn_mfma_f32_16x16x32_f16(af0, bf, acc[0], 0, 0, 0);
        acc[1] = __builtin_amdgcn_mfma_f32_16x16x32_f16(af1, bf, acc[1], 0, 0, 0);
    }
    __syncthreads();   // all reads of half A done

    // ---- phase 2.5b: write s8..14 (ks 32..59 -> local 0..27) ----
    #pragma unroll
    for (int pp = 0; pp < 4; ++pp)
        #pragma unroll
        for (int s = 8; s < 15; ++s) {
            union { __half2 h; unsigned u; } cv; cv.h = agg[pp][s];
            ((unsigned*)a_lds)[wbaseB[pp] + (s - 8) * 1024] = cv.u;
        }
    __syncthreads();

    // ---- phase 3b: MFMA ks 32..59 (ring holds 32..35 on entry) ----
    #pragma unroll
    for (int i = 0; i < 28; ++i) {
        const f16x8 bf = bq[i & 3];
        if (i + 4 < 28)
            bq[i & 3] = *(const f16x8*)(wp + (36 + i) * 512);
        const f16x8 af0 = *(const f16x8*)(a_bytes + rbB[0][i & 1]
                                          + (i >> 1) * 2048);
        const f16x8 af1 = *(const f16x8*)(a_bytes + rbB[1][i & 1]
                                          + (i >> 1) * 2048);
        acc[0] = __builtin_amdgcn_mfma_f32_16x16x32_f16(af0, bf, acc[0], 0, 0, 0);
        acc[1] = __builtin_amdgcn_mfma_f32_16x16x32_f16(af1, bf, acc[1], 0, 0, 0);
    }

    // ---- epilogue: C/D layout col=lane&15, row=(lane>>4)*4+reg ----
    const int col = lane & 15;
    const int rg  = lane >> 4;
    const int o   = wv * 16 + col;
    const float b = bias[o];
    #pragma unroll
    for (int mt = 0; mt < 2; ++mt) {
        #pragma unroll
        for (int r = 0; r < 4; ++r) {
            const int row = mt * 16 + rg * 4 + r;
            out[((size_t)(pt0 + row) << 7) + o] = acc[mt][r] + b;
        }
    }
}

extern "C" void kernel_launch(void* const* d_in, const int* in_sizes, int n_in,
                              void* d_out, int out_size, void* d_ws, size_t ws_size,
                              hipStream_t stream)
{
    const float* xyz  = (const float*)d_in[0];
    const float* feat = (const float*)d_in[1];
    const int*   nidx = (const int*)  d_in[2];
    const float* kpts = (const float*)d_in[3];
    const float* W    = (const float*)d_in[4];
    const float* bias = (const float*)d_in[5];
    float* out = (float*)d_out;

    unsigned short* Wp = (unsigned short*)d_ws;   // 491,520 B

    wpack_kernel<<<120, 256, 0, stream>>>(W, Wp);

    const int total_pts = in_sizes[0] / 3;        // 65536
    kpconv_main<<<total_pts / P, 512, 0, stream>>>(xyz, feat, nidx, kpts,
                                                   Wp, bias, out);
}